// Round 5
// baseline (410.359 us; speedup 1.0000x reference)
//
#include <hip/hip_runtime.h>
#include <cstdint>
#include <cstddef>

typedef __attribute__((ext_vector_type(8))) short bf16x8;    // 8 bf16 = 4 VGPRs
typedef __attribute__((ext_vector_type(4))) float f32x4;
typedef __attribute__((ext_vector_type(16))) float f32x16;

#define MFMA32(a, b, c) __builtin_amdgcn_mfma_f32_32x32x16_bf16((a), (b), (c), 0, 0, 0)

constexpr int Bz = 4, S = 2048, E = 1024, H = 16, Dh = 64;
constexpr size_t BSE = (size_t)Bz * S * E;   // 8388608
constexpr int LDP = 72;    // K-tile row stride (shorts): 36 dwords -> lane step 4 mod 32, clean
constexpr int VLD = 136;   // V^T-tile row stride (shorts): 68 dwords ≡ 4 mod 32, clean

__device__ __forceinline__ unsigned short f2bf(float f) {
    uint32_t u = __builtin_bit_cast(uint32_t, f);
    u += 0x7FFFu + ((u >> 16) & 1u);   // round-to-nearest-even
    return (unsigned short)(u >> 16);
}

// exp2 as a single v_exp_f32
__device__ __forceinline__ float exp2_fast(float x) {
#if __has_builtin(__builtin_amdgcn_exp2f)
    return __builtin_amdgcn_exp2f(x);
#else
    return exp2f(x);
#endif
}

// pack two floats to packed bf16 (round-half-up): 2 adds + 1 v_perm
__device__ __forceinline__ uint32_t pack_bf16(float a, float b) {
    uint32_t ua = __builtin_bit_cast(uint32_t, a) + 0x8000u;
    uint32_t ub = __builtin_bit_cast(uint32_t, b) + 0x8000u;
#if __has_builtin(__builtin_amdgcn_perm)
    return __builtin_amdgcn_perm(ub, ua, 0x07060302u);   // {ub.hi16, ua.hi16}
#else
    return (ua >> 16) | (ub & 0xFFFF0000u);
#endif
}

// ---------------- K convert + V transpose, one pass ----------------
// grid (S/64, H, B), block 256. K: [B,S,E] fp32 -> bf16 same layout.
// V: [B,S,H*Dh] fp32 -> [B,H,Dh,S] bf16 via LDS tile.
__global__ __launch_bounds__(256) void prep_kv(const float* __restrict__ k,
                                               const float* __restrict__ v,
                                               unsigned short* __restrict__ kb,
                                               unsigned short* __restrict__ vt) {
    __shared__ unsigned short tile[64][65];
    const int b = blockIdx.z, h = blockIdx.y, s0 = blockIdx.x * 64;
    const int r = threadIdx.x >> 2, cb = (threadIdx.x & 3) * 16;
    const size_t off = (size_t)(b * S + s0 + r) * E + h * Dh + cb;

    // K: convert in place (coalesced b128 out)
    {
        const float* src = k + off;
        uint32_t o[8];
#pragma unroll
        for (int j = 0; j < 8; ++j) {
            float2 f = *(const float2*)(src + 2 * j);
            o[j] = pack_bf16(f.x, f.y);
        }
        unsigned short* dst = kb + off;
        *(uint4*)(dst) = *(const uint4*)(o);
        *(uint4*)(dst + 8) = *(const uint4*)(o + 4);
    }
    // V: transpose via LDS
    {
        const float* src = v + off;
#pragma unroll
        for (int j = 0; j < 16; j += 4) {
            float4 f = *(const float4*)(src + j);
            tile[cb + j + 0][r] = f2bf(f.x);
            tile[cb + j + 1][r] = f2bf(f.y);
            tile[cb + j + 2][r] = f2bf(f.z);
            tile[cb + j + 3][r] = f2bf(f.w);
        }
    }
    __syncthreads();
    const int dv = threadIdx.x >> 2, seg = (threadIdx.x & 3) * 16;
    unsigned short* dst = vt + (((size_t)(b * H + h) * Dh + dv) * S + s0 + seg);
    *(uint4*)(dst) = *(const uint4*)(&tile[dv][seg]);
    *(uint4*)(dst + 8) = *(const uint4*)(&tile[dv][seg] + 8);
}

// ---------------- flash attention, S^T formulation, 32x32x16 MFMA ----------------
// grid: 1024 blocks; XCD-swizzled so the 16 q-blocks of one (b,h) share an XCD's L2.
// Register prefetch: tile kt+1 loaded into VGPRs during compute of kt, so the
// pre-ds_write vmcnt drain hits already-landed loads (kills the barrier stall).
__global__ __launch_bounds__(256, 4) void attn_kernel(const float* __restrict__ q,
                                                      const unsigned short* __restrict__ kb,
                                                      const unsigned short* __restrict__ vt,
                                                      unsigned short* __restrict__ attn) {
    __shared__ unsigned short smem[128 * LDP + 64 * VLD];
    unsigned short* Ks = smem;               // [key 0..127][d 0..63]   stride LDP
    unsigned short* Vts = smem + 128 * LDP;  // [dv 0..63][key 0..127]  stride VLD

    // XCD swizzle: wid -> (xcd c = wid&7, j = wid>>3); bh = c*8 + (j>>4); qblk = j&15
    const int wid = blockIdx.x + 16 * (blockIdx.y + 16 * blockIdx.z);
    const int c_ = wid & 7, j_ = wid >> 3;
    const int bh = c_ * 8 + (j_ >> 4), qblk = j_ & 15;
    const int b = bh >> 4, h = bh & 15;

    const int tid = threadIdx.x;
    const int wave = tid >> 6, lane = tid & 63;
    const int l32 = lane & 31, half = lane >> 5;

    const int q0 = qblk * 128 + wave * 32;
    const float scl = 0.125f * 1.44269504088896f;   // D^-0.5 * log2(e)

    // Q in registers (B-operand granules): qreg[t][j] = Q[q=l32][d=16t+half*8+j]
    bf16x8 qreg[4];
    {
        const float* qsrc = q + ((size_t)(b * S + q0 + l32)) * E + h * Dh + half * 8;
#pragma unroll
        for (int t = 0; t < 4; ++t) {
            float4 f0 = *(const float4*)(qsrc + 16 * t);
            float4 f1 = *(const float4*)(qsrc + 16 * t + 4);
            bf16x8 r;
            r[0] = (short)f2bf(f0.x * scl); r[1] = (short)f2bf(f0.y * scl);
            r[2] = (short)f2bf(f0.z * scl); r[3] = (short)f2bf(f0.w * scl);
            r[4] = (short)f2bf(f1.x * scl); r[5] = (short)f2bf(f1.y * scl);
            r[6] = (short)f2bf(f1.z * scl); r[7] = (short)f2bf(f1.w * scl);
            qreg[t] = r;
        }
    }

    f32x16 oacc[2];
#pragma unroll
    for (int mt = 0; mt < 2; ++mt)
#pragma unroll
        for (int r = 0; r < 16; ++r) oacc[mt][r] = 0.f;
    float lp0 = 0.f, lp1 = 0.f, lp2 = 0.f, lp3 = 0.f;

    const int krow = tid >> 1, kseg = (tid & 1) * 32;   // K: 128 rows x 64 shorts
    const int vrow = tid >> 2, vseg = (tid & 3) * 32;   // V^T: 64 rows x 128 shorts
    const unsigned short* kbase = kb + ((size_t)(b * S) * E + h * Dh);
    const unsigned short* vbase = vt + ((size_t)((b * H + h) * Dh + vrow) * S);

    uint4 kpre[4], vpre[4];
    {
        const uint4* ksrc = (const uint4*)(kbase + (size_t)krow * E + kseg);
#pragma unroll
        for (int u = 0; u < 4; ++u) kpre[u] = ksrc[u];
        const uint4* vsrc = (const uint4*)(vbase + vseg);
#pragma unroll
        for (int u = 0; u < 4; ++u) vpre[u] = vsrc[u];
    }

    for (int kt = 0; kt < S / 128; ++kt) {
        __syncthreads();   // prev iter's LDS reads done
        {
            uint4* kdst = (uint4*)(Ks + krow * LDP + kseg);
#pragma unroll
            for (int u = 0; u < 4; ++u) kdst[u] = kpre[u];
            uint4* vdst = (uint4*)(Vts + vrow * VLD + vseg);
#pragma unroll
            for (int u = 0; u < 4; ++u) vdst[u] = vpre[u];
        }
        __syncthreads();

        if (kt + 1 < S / 128) {   // prefetch next tile; lands during compute below
            const uint4* ksrc = (const uint4*)(kbase + (size_t)((kt + 1) * 128 + krow) * E + kseg);
#pragma unroll
            for (int u = 0; u < 4; ++u) kpre[u] = ksrc[u];
            const uint4* vsrc = (const uint4*)(vbase + (kt + 1) * 128 + vseg);
#pragma unroll
            for (int u = 0; u < 4; ++u) vpre[u] = vsrc[u];
        }

#pragma unroll
        for (int kh = 0; kh < 2; ++kh) {
            // S^T[key][q]: 2 key-tiles x 4 d-chunks
            f32x16 st[2];
#pragma unroll
            for (int mt = 0; mt < 2; ++mt) {
#pragma unroll
                for (int r = 0; r < 16; ++r) st[mt][r] = 0.f;
#pragma unroll
                for (int t = 0; t < 4; ++t) {
                    bf16x8 a = *(const bf16x8*)(Ks + (kh * 64 + mt * 32 + l32) * LDP +
                                                t * 16 + half * 8);
                    st[mt] = MFMA32(a, qreg[t], st[mt]);
                }
            }

            // p = exp2(s); pack key-pairs into dwords.
            // reg r of tile mt: key = (r&3) + 8*(r>>2) + 4*half + 32*mt, q = l32.
            uint32_t pkd[2][4][2];
#pragma unroll
            for (int mt = 0; mt < 2; ++mt)
#pragma unroll
                for (int g = 0; g < 4; ++g) {
                    float p0 = exp2_fast(st[mt][4 * g + 0]);
                    float p1 = exp2_fast(st[mt][4 * g + 1]);
                    float p2 = exp2_fast(st[mt][4 * g + 2]);
                    float p3 = exp2_fast(st[mt][4 * g + 3]);
                    lp0 += p0; lp1 += p1; lp2 += p2; lp3 += p3;
                    pkd[mt][g][0] = pack_bf16(p0, p1);
                    pkd[mt][g][1] = pack_bf16(p2, p3);
                }

            // O^T += V^T · P^T over 4 key-chunks of 16
#pragma unroll
            for (int c = 0; c < 4; ++c) {
                const int ms = c >> 1;
                const int g0 = 2 * (c & 1);
                uint32_t a0 = pkd[ms][g0][0], a1 = pkd[ms][g0][1];
                uint32_t b0 = pkd[ms][g0 + 1][0], b1 = pkd[ms][g0 + 1][1];
                uint32_t snd0 = half ? a0 : b0;
                uint32_t snd1 = half ? a1 : b1;
                uint32_t r0 = (uint32_t)__shfl_xor((int)snd0, 32);
                uint32_t r1 = (uint32_t)__shfl_xor((int)snd1, 32);
                int4 bi;
                bi.x = (int)(half ? r0 : a0);
                bi.y = (int)(half ? r1 : a1);
                bi.z = (int)(half ? b0 : r0);
                bi.w = (int)(half ? b1 : r1);
                bf16x8 bfrag = __builtin_bit_cast(bf16x8, bi);
#pragma unroll
                for (int mt = 0; mt < 2; ++mt) {
                    bf16x8 a = *(const bf16x8*)(Vts + (mt * 32 + l32) * VLD +
                                                kh * 64 + c * 16 + half * 8);
                    oacc[mt] = MFMA32(a, bfrag, oacc[mt]);
                }
            }
        }
    }

    // final row-sum across key-halves, then normalize
    __syncthreads();   // done reading K/V before smem reuse
    float l_part = (lp0 + lp1) + (lp2 + lp3);
    float l = l_part + (float)__shfl_xor(l_part, 32);
    float inv = 1.0f / l;

    // O^T -> per-wave LDS transpose buffer [q 0..31][dv 0..63], then coalesced store
    unsigned short* ob = smem + wave * (32 * LDP);
#pragma unroll
    for (int mt = 0; mt < 2; ++mt)
#pragma unroll
        for (int g = 0; g < 4; ++g) {
            int dv0 = 8 * g + 4 * half + 32 * mt;
            uint2 w2;
            w2.x = pack_bf16(oacc[mt][4 * g + 0] * inv, oacc[mt][4 * g + 1] * inv);
            w2.y = pack_bf16(oacc[mt][4 * g + 2] * inv, oacc[mt][4 * g + 3] * inv);
            *(uint2*)(ob + l32 * LDP + dv0) = w2;
        }
    __syncthreads();
    {
        int row = lane >> 1;
        int cg0 = (lane & 1) * 4;
        unsigned short* gdst = attn + ((size_t)(b * S + q0 + row)) * E + h * Dh;
#pragma unroll
        for (int j = 0; j < 4; ++j) {
            bf16x8 v8 = *(const bf16x8*)(ob + row * LDP + (cg0 + j) * 8);
            *(bf16x8*)(gdst + (cg0 + j) * 8) = v8;
        }
    }
}

// ---------------- projection GEMM: C[M,N] = A[M,K] @ W[N,K]^T + bias ----------------
// M=8192, N=1024, K=1024. BM=BN=128, BK=32; 4 waves (2x2), wave tile 64x64 as
// 2x2 of 32x32x16 MFMA. W read as fp32 and converted during staging (W fits L2).
// Register prefetch of next A/W tile across the barrier.
constexpr int PLD = 40;   // 20 dwords: lane-pair step 20 mod 32, conflict-clean for b128
__global__ __launch_bounds__(256, 4) void proj_kernel(const unsigned short* __restrict__ A,
                                                      const float* __restrict__ W,
                                                      const float* __restrict__ bias,
                                                      float* __restrict__ C) {
    __shared__ unsigned short As[128 * PLD];
    __shared__ unsigned short Bs[128 * PLD];
    const int tid = threadIdx.x;
    const int wave = tid >> 6, lane = tid & 63;
    const int l32 = lane & 31, half = lane >> 5;
    const int wm = wave >> 1, wn = wave & 1;
    const int m0 = blockIdx.x * 128, n0 = blockIdx.y * 128;

    f32x16 acc[2][2];
#pragma unroll
    for (int mi = 0; mi < 2; ++mi)
#pragma unroll
        for (int ni = 0; ni < 2; ++ni)
#pragma unroll
            for (int r = 0; r < 16; ++r) acc[mi][ni][r] = 0.f;

    const int srow = tid >> 1, scb = (tid & 1) * 16;

    uint4 apre[2];
    float4 wpre[4];
    {
        const uint4* asrc = (const uint4*)(A + (size_t)(m0 + srow) * 1024 + scb);
        apre[0] = asrc[0];
        apre[1] = asrc[1];
        const float4* wsrc = (const float4*)(W + (size_t)(n0 + srow) * 1024 + scb);
#pragma unroll
        for (int u = 0; u < 4; ++u) wpre[u] = wsrc[u];
    }

    for (int k0 = 0; k0 < 1024; k0 += 32) {
        __syncthreads();
        {
            uint4* adst = (uint4*)(As + srow * PLD + scb);
            adst[0] = apre[0];
            adst[1] = apre[1];
            uint32_t pw[8];
            const float* wf = (const float*)wpre;
#pragma unroll
            for (int j = 0; j < 8; ++j) pw[j] = pack_bf16(wf[2 * j], wf[2 * j + 1]);
            uint4* bdst = (uint4*)(Bs + srow * PLD + scb);
            bdst[0] = *(const uint4*)(pw);
            bdst[1] = *(const uint4*)(pw + 4);
        }
        __syncthreads();

        if (k0 + 32 < 1024) {
            const uint4* asrc = (const uint4*)(A + (size_t)(m0 + srow) * 1024 + k0 + 32 + scb);
            apre[0] = asrc[0];
            apre[1] = asrc[1];
            const float4* wsrc = (const float4*)(W + (size_t)(n0 + srow) * 1024 + k0 + 32 + scb);
#pragma unroll
            for (int u = 0; u < 4; ++u) wpre[u] = wsrc[u];
        }

        bf16x8 af[2][2], bfr[2][2];
#pragma unroll
        for (int ks = 0; ks < 2; ++ks) {
#pragma unroll
            for (int mi = 0; mi < 2; ++mi)
                af[ks][mi] = *(const bf16x8*)(As + (wm * 64 + mi * 32 + l32) * PLD +
                                              ks * 16 + half * 8);
#pragma unroll
            for (int ni = 0; ni < 2; ++ni)
                bfr[ks][ni] = *(const bf16x8*)(Bs + (wn * 64 + ni * 32 + l32) * PLD +
                                               ks * 16 + half * 8);
        }
#pragma unroll
        for (int ks = 0; ks < 2; ++ks)
#pragma unroll
            for (int mi = 0; mi < 2; ++mi)
#pragma unroll
                for (int ni = 0; ni < 2; ++ni)
                    acc[mi][ni] = MFMA32(af[ks][mi], bfr[ks][ni], acc[mi][ni]);
    }

    // epilogue: 32x32 C-layout row = (r&3)+8*(r>>2)+4*half, col = l32
    float bb[2];
#pragma unroll
    for (int ni = 0; ni < 2; ++ni) bb[ni] = bias[n0 + wn * 64 + ni * 32 + l32];
#pragma unroll
    for (int mi = 0; mi < 2; ++mi) {
#pragma unroll
        for (int ni = 0; ni < 2; ++ni) {
            const int col = n0 + wn * 64 + ni * 32 + l32;
#pragma unroll
            for (int r = 0; r < 16; ++r) {
                int row = m0 + wm * 64 + mi * 32 + (r & 3) + 8 * (r >> 2) + 4 * half;
                C[(size_t)row * 1024 + col] = acc[mi][ni][r] + bb[ni];
            }
        }
    }
}

extern "C" void kernel_launch(void* const* d_in, const int* in_sizes, int n_in,
                              void* d_out, int out_size, void* d_ws, size_t ws_size,
                              hipStream_t stream) {
    const float* q = (const float*)d_in[0];
    const float* k = (const float*)d_in[1];
    const float* v = (const float*)d_in[2];
    const float* w = (const float*)d_in[3];
    const float* bias = (const float*)d_in[4];
    float* out = (float*)d_out;

    unsigned short* ws = (unsigned short*)d_ws;
    unsigned short* kb = ws;                       // BSE bf16
    unsigned short* vt = kb + BSE;                 // BSE bf16, layout [B,H,Dh,S]
    unsigned short* attnb = vt + BSE;              // BSE bf16

    prep_kv<<<dim3(S / 64, H, Bz), dim3(256), 0, stream>>>(k, v, kb, vt);
    attn_kernel<<<dim3(S / 128, H, Bz), dim3(256), 0, stream>>>(q, kb, vt, attnb);
    proj_kernel<<<dim3((Bz * S) / 128, E / 128), dim3(256), 0, stream>>>(attnb, w, bias, out);
}

// Round 6
// 308.234 us; speedup vs baseline: 1.3313x; 1.3313x over previous
//
#include <hip/hip_runtime.h>
#include <cstdint>
#include <cstddef>

typedef __attribute__((ext_vector_type(8))) short bf16x8;    // 8 bf16 = 4 VGPRs
typedef __attribute__((ext_vector_type(4))) float f32x4;
typedef __attribute__((ext_vector_type(16))) float f32x16;

#define MFMA32(a, b, c) __builtin_amdgcn_mfma_f32_32x32x16_bf16((a), (b), (c), 0, 0, 0)

constexpr int Bz = 4, S = 2048, E = 1024, H = 16, Dh = 64;
constexpr size_t BSE = (size_t)Bz * S * E;   // 8388608

__device__ __forceinline__ unsigned short f2bf(float f) {
    uint32_t u = __builtin_bit_cast(uint32_t, f);
    u += 0x7FFFu + ((u >> 16) & 1u);   // round-to-nearest-even
    return (unsigned short)(u >> 16);
}

__device__ __forceinline__ float exp2_fast(float x) {
#if __has_builtin(__builtin_amdgcn_exp2f)
    return __builtin_amdgcn_exp2f(x);
#else
    return exp2f(x);
#endif
}

// pack two floats to packed bf16 (round-half-up): 2 adds + 1 v_perm
__device__ __forceinline__ uint32_t pack_bf16(float a, float b) {
    uint32_t ua = __builtin_bit_cast(uint32_t, a) + 0x8000u;
    uint32_t ub = __builtin_bit_cast(uint32_t, b) + 0x8000u;
#if __has_builtin(__builtin_amdgcn_perm)
    return __builtin_amdgcn_perm(ub, ua, 0x07060302u);   // {ub.hi16, ua.hi16}
#else
    return (ua >> 16) | (ub & 0xFFFF0000u);
#endif
}

// async global -> LDS, 16 B per lane; LDS dst = wave-uniform base + lane*16
__device__ __forceinline__ void gload16(const unsigned short* g, unsigned short* l) {
    __builtin_amdgcn_global_load_lds((const __attribute__((address_space(1))) void*)g,
                                     (__attribute__((address_space(3))) void*)l, 16, 0, 0);
}

// ---------------- fp32 -> bf16 convert (for W) ----------------
__global__ __launch_bounds__(256) void convert_kernel(const float* __restrict__ in,
                                                      unsigned short* __restrict__ out,
                                                      int n4) {
    int i = blockIdx.x * blockDim.x + threadIdx.x;
    if (i < n4) {
        float4 f = ((const float4*)in)[i];
        uint2 u;
        u.x = pack_bf16(f.x, f.y);
        u.y = pack_bf16(f.z, f.w);
        ((uint2*)out)[i] = u;
    }
}

// ---------------- K convert + V transpose, one pass ----------------
__global__ __launch_bounds__(256) void prep_kv(const float* __restrict__ k,
                                               const float* __restrict__ v,
                                               unsigned short* __restrict__ kb,
                                               unsigned short* __restrict__ vt) {
    __shared__ unsigned short tile[64][65];
    const int b = blockIdx.z, h = blockIdx.y, s0 = blockIdx.x * 64;
    const int r = threadIdx.x >> 2, cb = (threadIdx.x & 3) * 16;
    const size_t off = (size_t)(b * S + s0 + r) * E + h * Dh + cb;

    {   // K: convert in place (coalesced b128 out)
        const float* src = k + off;
        uint32_t o[8];
#pragma unroll
        for (int j = 0; j < 8; ++j) {
            float2 f = *(const float2*)(src + 2 * j);
            o[j] = pack_bf16(f.x, f.y);
        }
        unsigned short* dst = kb + off;
        *(uint4*)(dst) = *(const uint4*)(o);
        *(uint4*)(dst + 8) = *(const uint4*)(o + 4);
    }
    {   // V: transpose via LDS
        const float* src = v + off;
#pragma unroll
        for (int j = 0; j < 16; j += 4) {
            float4 f = *(const float4*)(src + j);
            tile[cb + j + 0][r] = f2bf(f.x);
            tile[cb + j + 1][r] = f2bf(f.y);
            tile[cb + j + 2][r] = f2bf(f.z);
            tile[cb + j + 3][r] = f2bf(f.w);
        }
    }
    __syncthreads();
    const int dv = threadIdx.x >> 2, seg = (threadIdx.x & 3) * 16;
    unsigned short* dst = vt + (((size_t)(b * H + h) * Dh + dv) * S + s0 + seg);
    *(uint4*)(dst) = *(const uint4*)(&tile[dv][seg]);
    *(uint4*)(dst + 8) = *(const uint4*)(&tile[dv][seg] + 8);
}

// ---------------- flash attention ----------------
// 64-key tiles, double-buffered LDS filled by async global_load_lds (zero VGPR
// cost). XOR-swizzled LDS layout: slot s of row r holds data granule s^(r&7)
// (swizzle applied on the *global* source address — permutes within one 128 B
// row segment, so coalescing is unharmed; LDS side must stay contiguous for
// global_load_lds). Fragment reads use slot = g ^ (row&7) -> conflict-free.
// One barrier per iteration; tile kt+1's loads are issued right after it and
// land during compute of tile kt, so the next barrier's vmcnt(0) drain is cheap.
__global__ __launch_bounds__(256, 4) void attn_kernel(const float* __restrict__ q,
                                                      const unsigned short* __restrict__ kb,
                                                      const unsigned short* __restrict__ vt,
                                                      unsigned short* __restrict__ attn) {
    __shared__ unsigned short smem[2 * 8192];   // 32 KB: 2 x (Ks 4096 + Vts 4096 shorts)

    // XCD swizzle: 16 q-blocks of one (b,h) share an XCD's L2
    const int wid = blockIdx.x + 16 * (blockIdx.y + 16 * blockIdx.z);
    const int c_ = wid & 7, j_ = wid >> 3;
    const int bh = c_ * 8 + (j_ >> 4), qblk = j_ & 15;
    const int b = bh >> 4, h = bh & 15;

    const int tid = threadIdx.x;
    const int wave = tid >> 6, lane = tid & 63;
    const int l32 = lane & 31, half = lane >> 5;

    const int q0 = qblk * 128 + wave * 32;
    const float scl = 0.125f * 1.44269504088896f;   // D^-0.5 * log2(e)

    // Q in registers (B-operand granules): qreg[t][j] = Q[q=l32][d=16t+half*8+j]
    bf16x8 qreg[4];
    {
        const float* qsrc = q + ((size_t)(b * S + q0 + l32)) * E + h * Dh + half * 8;
#pragma unroll
        for (int t = 0; t < 4; ++t) {
            float4 f0 = *(const float4*)(qsrc + 16 * t);
            float4 f1 = *(const float4*)(qsrc + 16 * t + 4);
            bf16x8 r;
            r[0] = (short)f2bf(f0.x * scl); r[1] = (short)f2bf(f0.y * scl);
            r[2] = (short)f2bf(f0.z * scl); r[3] = (short)f2bf(f0.w * scl);
            r[4] = (short)f2bf(f1.x * scl); r[5] = (short)f2bf(f1.y * scl);
            r[6] = (short)f2bf(f1.z * scl); r[7] = (short)f2bf(f1.w * scl);
            qreg[t] = r;
        }
    }

    f32x16 oacc[2];
#pragma unroll
    for (int mt = 0; mt < 2; ++mt)
#pragma unroll
        for (int r = 0; r < 16; ++r) oacc[mt][r] = 0.f;
    float lp0 = 0.f, lp1 = 0.f, lp2 = 0.f, lp3 = 0.f;

    // staging lane map: instr covers 8 rows x 128 B; lane -> (row8 = lane>>3,
    // slot = lane&7); source granule g = slot ^ row8 (row&7 == row8)
    const int row8 = lane >> 3;
    const int sg = (lane & 7) ^ row8;
    const unsigned short* kbase = kb + ((size_t)(b * S)) * E + h * Dh;
    const unsigned short* vtb = vt + ((size_t)(b * H + h) * Dh) * S;

    auto stage = [&](int kt, int bsel) {
        unsigned short* ksb = smem + bsel * 8192;
        unsigned short* vsb = ksb + 4096;
#pragma unroll
        for (int u = 0; u < 2; ++u) {
            const int r0 = wave * 16 + u * 8;
            gload16(kbase + (size_t)(kt * 64 + r0 + row8) * E + sg * 8, ksb + r0 * 64);
            gload16(vtb + (size_t)(r0 + row8) * S + kt * 64 + sg * 8, vsb + r0 * 64);
        }
    };

    constexpr int NT = S / 64;   // 32
    stage(0, 0);

    for (int kt = 0; kt < NT; ++kt) {
        const int cur = kt & 1;
        __syncthreads();   // vmcnt(0) drains tile-kt loads (in flight one full iter)
        if (kt + 1 < NT) stage(kt + 1, cur ^ 1);
        const unsigned short* ksb = smem + cur * 8192;
        const unsigned short* vsb = ksb + 4096;

        // S^T[key][q]: 2 key-tiles x 4 d-chunks
        f32x16 st[2];
#pragma unroll
        for (int mt = 0; mt < 2; ++mt) {
#pragma unroll
            for (int r = 0; r < 16; ++r) st[mt][r] = 0.f;
#pragma unroll
            for (int t = 0; t < 4; ++t) {
                const int slot = (t * 2 + half) ^ (l32 & 7);
                bf16x8 a = *(const bf16x8*)(ksb + (mt * 32 + l32) * 64 + slot * 8);
                st[mt] = MFMA32(a, qreg[t], st[mt]);
            }
        }

        // p = exp2(s); pack key-pairs into dwords.
        // reg r of tile mt: key = (r&3) + 8*(r>>2) + 4*half + 32*mt, q = l32.
        uint32_t pkd[2][4][2];
#pragma unroll
        for (int mt = 0; mt < 2; ++mt)
#pragma unroll
            for (int g = 0; g < 4; ++g) {
                float p0 = exp2_fast(st[mt][4 * g + 0]);
                float p1 = exp2_fast(st[mt][4 * g + 1]);
                float p2 = exp2_fast(st[mt][4 * g + 2]);
                float p3 = exp2_fast(st[mt][4 * g + 3]);
                lp0 += p0; lp1 += p1; lp2 += p2; lp3 += p3;
                pkd[mt][g][0] = pack_bf16(p0, p1);
                pkd[mt][g][1] = pack_bf16(p2, p3);
            }

        // O^T += V^T · P^T over 4 key-chunks of 16
#pragma unroll
        for (int c = 0; c < 4; ++c) {
            const int ms = c >> 1;
            const int g0 = 2 * (c & 1);
            uint32_t a0 = pkd[ms][g0][0], a1 = pkd[ms][g0][1];
            uint32_t b0 = pkd[ms][g0 + 1][0], b1 = pkd[ms][g0 + 1][1];
            uint32_t snd0 = half ? a0 : b0;
            uint32_t snd1 = half ? a1 : b1;
            uint32_t r0 = (uint32_t)__shfl_xor((int)snd0, 32);
            uint32_t r1 = (uint32_t)__shfl_xor((int)snd1, 32);
            int4 bi;
            bi.x = (int)(half ? r0 : a0);
            bi.y = (int)(half ? r1 : a1);
            bi.z = (int)(half ? b0 : r0);
            bi.w = (int)(half ? b1 : r1);
            bf16x8 bfrag = __builtin_bit_cast(bf16x8, bi);
            const int slot = (c * 2 + half) ^ (l32 & 7);
#pragma unroll
            for (int mt = 0; mt < 2; ++mt) {
                bf16x8 a = *(const bf16x8*)(vsb + (mt * 32 + l32) * 64 + slot * 8);
                oacc[mt] = MFMA32(a, bfrag, oacc[mt]);
            }
        }
    }

    // final row-sum across key-halves, then normalize
    __syncthreads();   // all LDS reads done before smem reuse
    float l_part = (lp0 + lp1) + (lp2 + lp3);
    float l = l_part + (float)__shfl_xor(l_part, 32);
    float inv = 1.0f / l;

    // O^T -> per-wave LDS transpose buffer [q 0..31][dv 0..63] (stride 72), store
    unsigned short* ob = smem + wave * (32 * 72);
#pragma unroll
    for (int mt = 0; mt < 2; ++mt)
#pragma unroll
        for (int g = 0; g < 4; ++g) {
            int dv0 = 8 * g + 4 * half + 32 * mt;
            uint2 w2;
            w2.x = pack_bf16(oacc[mt][4 * g + 0] * inv, oacc[mt][4 * g + 1] * inv);
            w2.y = pack_bf16(oacc[mt][4 * g + 2] * inv, oacc[mt][4 * g + 3] * inv);
            *(uint2*)(ob + l32 * 72 + dv0) = w2;
        }
    __syncthreads();
    {
        int row = lane >> 1;
        int cg0 = (lane & 1) * 4;
        unsigned short* gdst = attn + ((size_t)(b * S + q0 + row)) * E + h * Dh;
#pragma unroll
        for (int j = 0; j < 4; ++j) {
            bf16x8 v8 = *(const bf16x8*)(ob + row * 72 + (cg0 + j) * 8);
            *(bf16x8*)(gdst + (cg0 + j) * 8) = v8;
        }
    }
}

// ---------------- projection GEMM: C[M,N] = A[M,K] @ W[N,K]^T + bias ----------------
// W pre-converted to bf16. BM=BN=128, BK=32; 4 waves (2x2), wave tile 64x64 as
// 2x2 of 32x32x16 MFMA. Small (16-VGPR) register prefetch; __launch_bounds__(256,2)
// leaves 256 VGPRs -> no spill (grid is 2 blocks/CU anyway).
constexpr int PLD = 40;   // padded stride (shorts): conflict-free frag reads
__global__ __launch_bounds__(256, 2) void proj_kernel(const unsigned short* __restrict__ A,
                                                      const unsigned short* __restrict__ W,
                                                      const float* __restrict__ bias,
                                                      float* __restrict__ C) {
    __shared__ unsigned short As[128 * PLD];
    __shared__ unsigned short Bs[128 * PLD];
    const int tid = threadIdx.x;
    const int wave = tid >> 6, lane = tid & 63;
    const int l32 = lane & 31, half = lane >> 5;
    const int wm = wave >> 1, wn = wave & 1;
    const int m0 = blockIdx.x * 128, n0 = blockIdx.y * 128;

    f32x16 acc[2][2];
#pragma unroll
    for (int mi = 0; mi < 2; ++mi)
#pragma unroll
        for (int ni = 0; ni < 2; ++ni)
#pragma unroll
            for (int r = 0; r < 16; ++r) acc[mi][ni][r] = 0.f;

    const int srow = tid >> 1, scb = (tid & 1) * 16;

    uint4 apre[2], wpre[2];
    {
        const uint4* asrc = (const uint4*)(A + (size_t)(m0 + srow) * 1024 + scb);
        apre[0] = asrc[0];
        apre[1] = asrc[1];
        const uint4* wsrc = (const uint4*)(W + (size_t)(n0 + srow) * 1024 + scb);
        wpre[0] = wsrc[0];
        wpre[1] = wsrc[1];
    }

    for (int k0 = 0; k0 < 1024; k0 += 32) {
        __syncthreads();
        {
            uint4* adst = (uint4*)(As + srow * PLD + scb);
            adst[0] = apre[0];
            adst[1] = apre[1];
            uint4* bdst = (uint4*)(Bs + srow * PLD + scb);
            bdst[0] = wpre[0];
            bdst[1] = wpre[1];
        }
        __syncthreads();

        if (k0 + 32 < 1024) {   // prefetch next tiles; land during MFMA below
            const uint4* asrc = (const uint4*)(A + (size_t)(m0 + srow) * 1024 + k0 + 32 + scb);
            apre[0] = asrc[0];
            apre[1] = asrc[1];
            const uint4* wsrc = (const uint4*)(W + (size_t)(n0 + srow) * 1024 + k0 + 32 + scb);
            wpre[0] = wsrc[0];
            wpre[1] = wsrc[1];
        }

        bf16x8 af[2][2], bfr[2][2];
#pragma unroll
        for (int ks = 0; ks < 2; ++ks) {
#pragma unroll
            for (int mi = 0; mi < 2; ++mi)
                af[ks][mi] = *(const bf16x8*)(As + (wm * 64 + mi * 32 + l32) * PLD +
                                              ks * 16 + half * 8);
#pragma unroll
            for (int ni = 0; ni < 2; ++ni)
                bfr[ks][ni] = *(const bf16x8*)(Bs + (wn * 64 + ni * 32 + l32) * PLD +
                                               ks * 16 + half * 8);
        }
#pragma unroll
        for (int ks = 0; ks < 2; ++ks)
#pragma unroll
            for (int mi = 0; mi < 2; ++mi)
#pragma unroll
                for (int ni = 0; ni < 2; ++ni)
                    acc[mi][ni] = MFMA32(af[ks][mi], bfr[ks][ni], acc[mi][ni]);
    }

    // epilogue: 32x32 C-layout row = (r&3)+8*(r>>2)+4*half, col = l32
    float bb[2];
#pragma unroll
    for (int ni = 0; ni < 2; ++ni) bb[ni] = bias[n0 + wn * 64 + ni * 32 + l32];
#pragma unroll
    for (int mi = 0; mi < 2; ++mi) {
#pragma unroll
        for (int ni = 0; ni < 2; ++ni) {
            const int col = n0 + wn * 64 + ni * 32 + l32;
#pragma unroll
            for (int r = 0; r < 16; ++r) {
                int row = m0 + wm * 64 + mi * 32 + (r & 3) + 8 * (r >> 2) + 4 * half;
                C[(size_t)row * 1024 + col] = acc[mi][ni][r] + bb[ni];
            }
        }
    }
}

extern "C" void kernel_launch(void* const* d_in, const int* in_sizes, int n_in,
                              void* d_out, int out_size, void* d_ws, size_t ws_size,
                              hipStream_t stream) {
    const float* q = (const float*)d_in[0];
    const float* k = (const float*)d_in[1];
    const float* v = (const float*)d_in[2];
    const float* w = (const float*)d_in[3];
    const float* bias = (const float*)d_in[4];
    float* out = (float*)d_out;

    unsigned short* ws = (unsigned short*)d_ws;
    unsigned short* kb = ws;                       // BSE bf16
    unsigned short* vt = kb + BSE;                 // BSE bf16, layout [B,H,Dh,S]
    unsigned short* attnb = vt + BSE;              // BSE bf16
    unsigned short* wb = attnb + BSE;              // E*E bf16

    prep_kv<<<dim3(S / 64, H, Bz), dim3(256), 0, stream>>>(k, v, kb, vt);
    {
        int nw4 = (int)((size_t)E * E / 4);
        convert_kernel<<<dim3((nw4 + 255) / 256), dim3(256), 0, stream>>>(w, wb, nw4);
    }
    attn_kernel<<<dim3(S / 128, H, Bz), dim3(256), 0, stream>>>(q, kb, vt, attnb);
    proj_kernel<<<dim3((Bz * S) / 128, E / 128), dim3(256), 0, stream>>>(attnb, wb, bias, out);
}

// Round 7
// 255.478 us; speedup vs baseline: 1.6062x; 1.2065x over previous
//
#include <hip/hip_runtime.h>
#include <cstdint>
#include <cstddef>

typedef __attribute__((ext_vector_type(8))) short bf16x8;    // 8 bf16 = 4 VGPRs
typedef __attribute__((ext_vector_type(4))) float f32x4;
typedef __attribute__((ext_vector_type(16))) float f32x16;

#define MFMA16(a, b, c) __builtin_amdgcn_mfma_f32_16x16x32_bf16((a), (b), (c), 0, 0, 0)
#define MFMA32(a, b, c) __builtin_amdgcn_mfma_f32_32x32x16_bf16((a), (b), (c), 0, 0, 0)

constexpr int Bz = 4, S = 2048, E = 1024, H = 16, Dh = 64;
constexpr size_t BSE = (size_t)Bz * S * E;   // 8388608

__device__ __forceinline__ unsigned short f2bf(float f) {
    uint32_t u = __builtin_bit_cast(uint32_t, f);
    u += 0x7FFFu + ((u >> 16) & 1u);   // round-to-nearest-even
    return (unsigned short)(u >> 16);
}

__device__ __forceinline__ float exp2_fast(float x) {
#if __has_builtin(__builtin_amdgcn_exp2f)
    return __builtin_amdgcn_exp2f(x);
#else
    return exp2f(x);
#endif
}

// pack two floats to packed bf16 (round-half-up): 2 adds + 1 v_perm
__device__ __forceinline__ uint32_t pack_bf16(float a, float b) {
    uint32_t ua = __builtin_bit_cast(uint32_t, a) + 0x8000u;
    uint32_t ub = __builtin_bit_cast(uint32_t, b) + 0x8000u;
#if __has_builtin(__builtin_amdgcn_perm)
    return __builtin_amdgcn_perm(ub, ua, 0x07060302u);   // {ub.hi16, ua.hi16}
#else
    return (ua >> 16) | (ub & 0xFFFF0000u);
#endif
}

// async global -> LDS, 16 B per lane; LDS dst = wave-uniform base + lane*16
__device__ __forceinline__ void gload16(const unsigned short* g, unsigned short* l) {
    __builtin_amdgcn_global_load_lds((const __attribute__((address_space(1))) void*)g,
                                     (__attribute__((address_space(3))) void*)l, 16, 0, 0);
}

// ---------------- fp32 -> bf16 convert (for W) ----------------
__global__ __launch_bounds__(256) void convert_kernel(const float* __restrict__ in,
                                                      unsigned short* __restrict__ out,
                                                      int n4) {
    int i = blockIdx.x * blockDim.x + threadIdx.x;
    if (i < n4) {
        float4 f = ((const float4*)in)[i];
        uint2 u;
        u.x = pack_bf16(f.x, f.y);
        u.y = pack_bf16(f.z, f.w);
        ((uint2*)out)[i] = u;
    }
}

// ---------------- K convert + V transpose, one pass ----------------
__global__ __launch_bounds__(256) void prep_kv(const float* __restrict__ k,
                                               const float* __restrict__ v,
                                               unsigned short* __restrict__ kb,
                                               unsigned short* __restrict__ vt) {
    __shared__ unsigned short tile[64][65];
    const int b = blockIdx.z, h = blockIdx.y, s0 = blockIdx.x * 64;
    const int r = threadIdx.x >> 2, cb = (threadIdx.x & 3) * 16;
    const size_t off = (size_t)(b * S + s0 + r) * E + h * Dh + cb;

    {   // K: convert in place (coalesced b128 out)
        const float* src = k + off;
        uint32_t o[8];
#pragma unroll
        for (int j = 0; j < 8; ++j) {
            float2 f = *(const float2*)(src + 2 * j);
            o[j] = pack_bf16(f.x, f.y);
        }
        unsigned short* dst = kb + off;
        *(uint4*)(dst) = *(const uint4*)(o);
        *(uint4*)(dst + 8) = *(const uint4*)(o + 4);
    }
    {   // V: transpose via LDS
        const float* src = v + off;
#pragma unroll
        for (int j = 0; j < 16; j += 4) {
            float4 f = *(const float4*)(src + j);
            tile[cb + j + 0][r] = f2bf(f.x);
            tile[cb + j + 1][r] = f2bf(f.y);
            tile[cb + j + 2][r] = f2bf(f.z);
            tile[cb + j + 3][r] = f2bf(f.w);
        }
    }
    __syncthreads();
    const int dv = threadIdx.x >> 2, seg = (threadIdx.x & 3) * 16;
    unsigned short* dst = vt + (((size_t)(b * H + h) * Dh + dv) * S + s0 + seg);
    *(uint4*)(dst) = *(const uint4*)(&tile[dv][seg]);
    *(uint4*)(dst + 8) = *(const uint4*)(&tile[dv][seg] + 8);
}

// ---------------- flash attention ----------------
// 64 q-rows per wave (256 q per block), 64-key double-buffered async-staged
// tiles. K/V fragments read from LDS ONCE per iter and reused by both q-halves
// -> LDS reads per FLOP halved vs 32q/wave. Group-padded LDS: 8-row groups at
// stride 528 shorts (8 dwords mod 32 banks) + XOR slot swizzle -> row-aliased
// lanes hit different banks; within-group contiguous (global_load_lds-legal).
constexpr int GSTR = 528;   // 8-row group stride in shorts
__global__ __launch_bounds__(256, 2) void attn_kernel(const float* __restrict__ q,
                                                      const unsigned short* __restrict__ kb,
                                                      const unsigned short* __restrict__ vt,
                                                      unsigned short* __restrict__ attn) {
    __shared__ unsigned short smem[18432];   // 36 KB: 2 x (K 4224 + V 4224); epilogue 4x64x72

    // XCD swizzle: the 8 q-blocks of one (b,h) share an XCD's L2
    const int wid = blockIdx.x + 8 * (blockIdx.y + 16 * blockIdx.z);
    const int c_ = wid & 7, j_ = wid >> 3;
    const int bh = c_ * 8 + (j_ >> 3), qblk = j_ & 7;
    const int b = bh >> 4, h = bh & 15;

    const int tid = threadIdx.x;
    const int wave = tid >> 6, lane = tid & 63;
    const int l32 = lane & 31, half = lane >> 5;
    const int x7 = l32 & 7, y4 = l32 >> 3;

    const int q0 = qblk * 256 + wave * 64;
    const float scl = 0.125f * 1.44269504088896f;   // D^-0.5 * log2(e)

    // Q in registers: qreg[qh][t][j] = Q[q = q0+qh*32+l32][d = 16t + half*8 + j]
    bf16x8 qreg[2][4];
#pragma unroll
    for (int qh = 0; qh < 2; ++qh) {
        const float* qsrc = q + ((size_t)(b * S + q0 + qh * 32 + l32)) * E + h * Dh + half * 8;
#pragma unroll
        for (int t = 0; t < 4; ++t) {
            float4 f0 = *(const float4*)(qsrc + 16 * t);
            float4 f1 = *(const float4*)(qsrc + 16 * t + 4);
            bf16x8 r;
            r[0] = (short)f2bf(f0.x * scl); r[1] = (short)f2bf(f0.y * scl);
            r[2] = (short)f2bf(f0.z * scl); r[3] = (short)f2bf(f0.w * scl);
            r[4] = (short)f2bf(f1.x * scl); r[5] = (short)f2bf(f1.y * scl);
            r[6] = (short)f2bf(f1.z * scl); r[7] = (short)f2bf(f1.w * scl);
            qreg[qh][t] = r;
        }
    }

    f32x16 fzero;
#pragma unroll
    for (int r = 0; r < 16; ++r) fzero[r] = 0.f;
    f32x16 oacc[2][2];
#pragma unroll
    for (int qh = 0; qh < 2; ++qh)
#pragma unroll
        for (int mt = 0; mt < 2; ++mt) oacc[qh][mt] = fzero;
    float lsum[2] = {0.f, 0.f};

    // staging: one gload16 covers 8 rows x 128 B; lane -> (row8 = lane>>3,
    // slot = lane&7); fetch granule sg = slot ^ row8
    const int row8 = lane >> 3;
    const int sg = (lane & 7) ^ row8;
    const unsigned short* kbase = kb + ((size_t)(b * S)) * E + h * Dh;
    const unsigned short* vtb = vt + ((size_t)(b * H + h) * Dh) * S;

    auto stage = [&](int kt, int bsel) {
        unsigned short* ksb = smem + bsel * 8448;
        unsigned short* vsb = ksb + 4224;
#pragma unroll
        for (int u = 0; u < 2; ++u) {
            const int gi = wave * 2 + u;
            gload16(kbase + (size_t)(kt * 64 + gi * 8 + row8) * E + sg * 8, ksb + gi * GSTR);
            gload16(vtb + (size_t)(gi * 8 + row8) * S + kt * 64 + sg * 8, vsb + gi * GSTR);
        }
    };

    // per-lane row offsets for fragment reads (row r = mt*32 + l32)
    int roff[2];
#pragma unroll
    for (int mt = 0; mt < 2; ++mt) roff[mt] = (mt * 4 + y4) * GSTR + x7 * 64;

    constexpr int NT = S / 64;   // 32
    stage(0, 0);

    for (int kt = 0; kt < NT; ++kt) {
        const int cur = kt & 1;
        __syncthreads();   // drains tile-kt loads (in flight one full iteration)
        if (kt + 1 < NT) stage(kt + 1, cur ^ 1);
        const unsigned short* ksb = smem + cur * 8448;
        const unsigned short* vsb = ksb + 4224;

        // K fragments once per iter (shared by both q-halves)
        bf16x8 kfrag[2][4];
#pragma unroll
        for (int mt = 0; mt < 2; ++mt)
#pragma unroll
            for (int t = 0; t < 4; ++t)
                kfrag[mt][t] = *(const bf16x8*)(ksb + roff[mt] + (((t * 2 + half) ^ x7) * 8));

        // S^T[key][q] both q-halves
        f32x16 st[2][2];
#pragma unroll
        for (int qh = 0; qh < 2; ++qh)
#pragma unroll
            for (int mt = 0; mt < 2; ++mt) {
                st[qh][mt] = MFMA32(kfrag[mt][0], qreg[qh][0], fzero);
#pragma unroll
                for (int t = 1; t < 4; ++t)
                    st[qh][mt] = MFMA32(kfrag[mt][t], qreg[qh][t], st[qh][mt]);
            }

        // p = exp2(s); pack key-pairs. reg r of tile mt: key = (r&3)+8*(r>>2)+4*half+32*mt
        uint32_t pkd[2][2][4][2];
#pragma unroll
        for (int qh = 0; qh < 2; ++qh) {
            float ls = 0.f;
#pragma unroll
            for (int mt = 0; mt < 2; ++mt)
#pragma unroll
                for (int g = 0; g < 4; ++g) {
                    float p0 = exp2_fast(st[qh][mt][4 * g + 0]);
                    float p1 = exp2_fast(st[qh][mt][4 * g + 1]);
                    float p2 = exp2_fast(st[qh][mt][4 * g + 2]);
                    float p3 = exp2_fast(st[qh][mt][4 * g + 3]);
                    ls += (p0 + p1) + (p2 + p3);
                    pkd[qh][mt][g][0] = pack_bf16(p0, p1);
                    pkd[qh][mt][g][1] = pack_bf16(p2, p3);
                }
            lsum[qh] += ls;
        }

        // V^T fragments once per iter
        bf16x8 vfrag[2][4];
#pragma unroll
        for (int mt = 0; mt < 2; ++mt)
#pragma unroll
            for (int c = 0; c < 4; ++c)
                vfrag[mt][c] = *(const bf16x8*)(vsb + roff[mt] + (((c * 2 + half) ^ x7) * 8));

        // O^T += V^T · P^T
#pragma unroll
        for (int qh = 0; qh < 2; ++qh)
#pragma unroll
            for (int c = 0; c < 4; ++c) {
                const int ms = c >> 1;
                const int g0 = 2 * (c & 1);
                uint32_t a0 = pkd[qh][ms][g0][0], a1 = pkd[qh][ms][g0][1];
                uint32_t b0 = pkd[qh][ms][g0 + 1][0], b1 = pkd[qh][ms][g0 + 1][1];
                uint32_t snd0 = half ? a0 : b0;
                uint32_t snd1 = half ? a1 : b1;
                uint32_t r0 = (uint32_t)__shfl_xor((int)snd0, 32);
                uint32_t r1 = (uint32_t)__shfl_xor((int)snd1, 32);
                int4 bi;
                bi.x = (int)(half ? r0 : a0);
                bi.y = (int)(half ? r1 : a1);
                bi.z = (int)(half ? b0 : r0);
                bi.w = (int)(half ? b1 : r1);
                bf16x8 bfrag = __builtin_bit_cast(bf16x8, bi);
#pragma unroll
                for (int mt = 0; mt < 2; ++mt)
                    oacc[qh][mt] = MFMA32(vfrag[mt][c], bfrag, oacc[qh][mt]);
            }
    }

    // row sums across key-halves, normalize, transpose via LDS, store
    __syncthreads();   // all LDS reads done before smem reuse
    float inv[2];
#pragma unroll
    for (int qh = 0; qh < 2; ++qh) {
        float l = lsum[qh] + (float)__shfl_xor(lsum[qh], 32);
        inv[qh] = 1.0f / l;
    }

    unsigned short* ob = smem + wave * (64 * 72);   // [qrow 0..63][dv 0..63] stride 72
#pragma unroll
    for (int qh = 0; qh < 2; ++qh)
#pragma unroll
        for (int mt = 0; mt < 2; ++mt)
#pragma unroll
            for (int g = 0; g < 4; ++g) {
                int dv0 = 8 * g + 4 * half + 32 * mt;
                uint2 w2;
                w2.x = pack_bf16(oacc[qh][mt][4 * g + 0] * inv[qh],
                                 oacc[qh][mt][4 * g + 1] * inv[qh]);
                w2.y = pack_bf16(oacc[qh][mt][4 * g + 2] * inv[qh],
                                 oacc[qh][mt][4 * g + 3] * inv[qh]);
                *(uint2*)(ob + (qh * 32 + l32) * 72 + dv0) = w2;
            }
    __syncthreads();
#pragma unroll
    for (int it = 0; it < 2; ++it) {
        int row = it * 32 + (lane >> 1);
        int seg = (lane & 1) * 32;
        unsigned short* gdst = attn + ((size_t)(b * S + q0 + row)) * E + h * Dh + seg;
#pragma unroll
        for (int j = 0; j < 4; ++j) {
            bf16x8 v8 = *(const bf16x8*)(ob + row * 72 + seg + j * 8);
            *(bf16x8*)(gdst + j * 8) = v8;
        }
    }
}

// ---------------- projection GEMM (R4-known-good): C = A @ W^T + bias ----------------
// M=8192, N=1024, K=1024. BM=BN=128, BK=32; 4 waves (2x2), each wave 64x64.
constexpr int PLD = 40;   // padded stride (shorts): conflict-free frag reads
__global__ __launch_bounds__(256) void proj_kernel(const unsigned short* __restrict__ A,
                                                   const unsigned short* __restrict__ W,
                                                   const float* __restrict__ bias,
                                                   float* __restrict__ C) {
    __shared__ unsigned short As[128 * PLD];
    __shared__ unsigned short Bs[128 * PLD];
    const int tid = threadIdx.x;
    const int wave = tid >> 6, lane = tid & 63, quad = lane >> 4, l16 = lane & 15;
    const int wm = wave >> 1, wn = wave & 1;
    const int m0 = blockIdx.x * 128, n0 = blockIdx.y * 128;

    f32x4 acc[4][4];
    f32x4 zero = {0.f, 0.f, 0.f, 0.f};
#pragma unroll
    for (int mi = 0; mi < 4; ++mi)
#pragma unroll
        for (int ni = 0; ni < 4; ++ni) acc[mi][ni] = zero;

    const int srow = tid >> 1, scb = (tid & 1) * 16;

    for (int k0 = 0; k0 < 1024; k0 += 32) {
        __syncthreads();
        {
            const uint4* asrc = (const uint4*)(A + (size_t)(m0 + srow) * 1024 + k0 + scb);
            uint4* adst = (uint4*)(As + srow * PLD + scb);
            adst[0] = asrc[0];
            adst[1] = asrc[1];
            const uint4* bsrc = (const uint4*)(W + (size_t)(n0 + srow) * 1024 + k0 + scb);
            uint4* bdst = (uint4*)(Bs + srow * PLD + scb);
            bdst[0] = bsrc[0];
            bdst[1] = bsrc[1];
        }
        __syncthreads();

        bf16x8 af[4], bfr[4];
#pragma unroll
        for (int mi = 0; mi < 4; ++mi)
            af[mi] = *(const bf16x8*)(As + (wm * 64 + mi * 16 + l16) * PLD + quad * 8);
#pragma unroll
        for (int ni = 0; ni < 4; ++ni)
            bfr[ni] = *(const bf16x8*)(Bs + (wn * 64 + ni * 16 + l16) * PLD + quad * 8);
#pragma unroll
        for (int mi = 0; mi < 4; ++mi)
#pragma unroll
            for (int ni = 0; ni < 4; ++ni)
                acc[mi][ni] = MFMA16(af[mi], bfr[ni], acc[mi][ni]);
    }

    float bb[4];
#pragma unroll
    for (int ni = 0; ni < 4; ++ni) bb[ni] = bias[n0 + wn * 64 + ni * 16 + l16];
#pragma unroll
    for (int mi = 0; mi < 4; ++mi) {
        const int row = m0 + wm * 64 + mi * 16 + quad * 4;
#pragma unroll
        for (int ni = 0; ni < 4; ++ni) {
            const int col = n0 + wn * 64 + ni * 16 + l16;
#pragma unroll
            for (int r = 0; r < 4; ++r)
                C[(size_t)(row + r) * 1024 + col] = acc[mi][ni][r] + bb[ni];
        }
    }
}

extern "C" void kernel_launch(void* const* d_in, const int* in_sizes, int n_in,
                              void* d_out, int out_size, void* d_ws, size_t ws_size,
                              hipStream_t stream) {
    const float* q = (const float*)d_in[0];
    const float* k = (const float*)d_in[1];
    const float* v = (const float*)d_in[2];
    const float* w = (const float*)d_in[3];
    const float* bias = (const float*)d_in[4];
    float* out = (float*)d_out;

    unsigned short* ws = (unsigned short*)d_ws;
    unsigned short* kb = ws;                       // BSE bf16
    unsigned short* vt = kb + BSE;                 // BSE bf16, layout [B,H,Dh,S]
    unsigned short* attnb = vt + BSE;              // BSE bf16
    unsigned short* wb = attnb + BSE;              // E*E bf16

    prep_kv<<<dim3(S / 64, H, Bz), dim3(256), 0, stream>>>(k, v, kb, vt);
    {
        int nw4 = (int)((size_t)E * E / 4);
        convert_kernel<<<dim3((nw4 + 255) / 256), dim3(256), 0, stream>>>(w, wb, nw4);
    }
    attn_kernel<<<dim3(S / 256, H, Bz), dim3(256), 0, stream>>>(q, kb, vt, attnb);
    proj_kernel<<<dim3((Bz * S) / 128, E / 128), dim3(256), 0, stream>>>(attnb, wb, bias, out);
}